// Round 7
// baseline (211.917 us; speedup 1.0000x reference)
//
#include <hip/hip_runtime.h>
#include <hip/hip_fp16.h>

#define D 64

typedef _Float16 h16;
typedef h16 h16x2 __attribute__((ext_vector_type(2)));

__device__ __forceinline__ h16x2 u2h(unsigned int u) {
    union { unsigned int i; h16x2 h; } t; t.i = u; return t.h;
}

// dot of 8 f16 pairs (two uint4-packed rows), f32 accumulate
__device__ __forceinline__ float dot8_f16(uint4 a, uint4 b, float c) {
#if __has_builtin(__builtin_amdgcn_fdot2)
    c = __builtin_amdgcn_fdot2(u2h(a.x), u2h(b.x), c, false);
    c = __builtin_amdgcn_fdot2(u2h(a.y), u2h(b.y), c, false);
    c = __builtin_amdgcn_fdot2(u2h(a.z), u2h(b.z), c, false);
    c = __builtin_amdgcn_fdot2(u2h(a.w), u2h(b.w), c, false);
    return c;
#else
    float2 t, s;
    t = __half22float2(*(const __half2*)&a.x); s = __half22float2(*(const __half2*)&b.x);
    c = fmaf(t.x, s.x, c); c = fmaf(t.y, s.y, c);
    t = __half22float2(*(const __half2*)&a.y); s = __half22float2(*(const __half2*)&b.y);
    c = fmaf(t.x, s.x, c); c = fmaf(t.y, s.y, c);
    t = __half22float2(*(const __half2*)&a.z); s = __half22float2(*(const __half2*)&b.z);
    c = fmaf(t.x, s.x, c); c = fmaf(t.y, s.y, c);
    t = __half22float2(*(const __half2*)&a.w); s = __half22float2(*(const __half2*)&b.w);
    c = fmaf(t.x, s.x, c); c = fmaf(t.y, s.y, c);
    return c;
#endif
}

// ---------------------------------------------------------------------------
// Kernel 1 (merged): blocks [0, gemmBlocks) compute Xp = f16(X @ W);
// blocks [gemmBlocks, ...) build CSR rowptr from sorted `row`.
// Block 0 also zeroes the work-stealing counter for the fused kernel.
// ---------------------------------------------------------------------------
__global__ __launch_bounds__(256) void prep_kernel(const float* __restrict__ X,
                                                   const float* __restrict__ W,
                                                   const int* __restrict__ row,
                                                   __half* __restrict__ Xp,
                                                   int* __restrict__ rowptr,
                                                   int* __restrict__ workCtr,
                                                   int nNodes, int nEdges,
                                                   int gemmBlocks) {
    if (blockIdx.x == 0 && threadIdx.x == 0) *workCtr = 0;

    if ((int)blockIdx.x >= gemmBlocks) {
        int e = (blockIdx.x - gemmBlocks) * 256 + threadIdx.x;
        if (e >= nEdges) return;
        int r = row[e];
        int rprev = (e == 0) ? -1 : row[e - 1];
        for (int q = rprev + 1; q <= r; ++q) rowptr[q] = e;
        if (e == nEdges - 1) {
            for (int q = r + 1; q <= nNodes; ++q) rowptr[q] = nEdges;
        }
        return;
    }
    int lane = threadIdx.x & 63;
    int wave = (blockIdx.x * 256 + threadIdx.x) >> 6;
    int nWaves = gemmBlocks * 4;

    float w[D];
#pragma unroll
    for (int k = 0; k < D; ++k) w[k] = W[k * D + lane];

    for (int r = wave; r < nNodes; r += nWaves) {
        int rr = __builtin_amdgcn_readfirstlane(r);
        const float4* xr = (const float4*)(X + (size_t)rr * D);
        float acc = 0.f;
#pragma unroll
        for (int k4 = 0; k4 < D / 4; ++k4) {
            float4 xv = xr[k4];
            acc = fmaf(xv.x, w[4 * k4 + 0], acc);
            acc = fmaf(xv.y, w[4 * k4 + 1], acc);
            acc = fmaf(xv.z, w[4 * k4 + 2], acc);
            acc = fmaf(xv.w, w[4 * k4 + 3], acc);
        }
        Xp[(size_t)rr * D + lane] = __float2half(acc);
    }
}

// ---------------------------------------------------------------------------
// Kernel 2: fused SDDMM + SpMM, persistent waves + dynamic work-stealing.
// Each wave grabs one octet (8 nodes) at a time via atomicAdd -> perfect
// cross-CU / cross-wave load balance. One 8-lane group per node; lane j
// holds dims 8j..8j+7 (one uint4 of f16). 4-edge batches, software-
// pipelined gathers; dot = 4 x v_dot2_f32_f16 + 3-shfl in-group reduce;
// accumulate = 4 x v_pk_fma_f16 (f16 accumulator, no per-edge converts).
// attn applied once in the f32 epilogue. No atomics on the output.
// ---------------------------------------------------------------------------
__global__ __launch_bounds__(256) void fused_kernel(const __half* __restrict__ Xp,
                                                    const int* __restrict__ rowptr,
                                                    const int* __restrict__ col,
                                                    const float* __restrict__ attn_w,
                                                    int* __restrict__ workCtr,
                                                    float* __restrict__ out,
                                                    int nNodes) {
    int lane = threadIdx.x & 63;
    int g = lane >> 3;        // node slot within wave
    int j = lane & 7;         // dim chunk: dims 8j..8j+7
    int nOct = (nNodes + 7) >> 3;
    float attn = attn_w[0];
    const uint4* XpV = (const uint4*)Xp;              // row stride = 8 uint4

    for (;;) {
        int oct;
        if (lane == 0) oct = atomicAdd(workCtr, 1);
        oct = __shfl(oct, 0, 64);
        if (oct >= nOct) break;

        int node = oct * 8 + g;
        bool active = node < nNodes;
        int nd = active ? node : 0;

        int eStart = rowptr[nd];
        int eEnd   = active ? rowptr[nd + 1] : eStart;

        uint4 xr = XpV[(size_t)nd * 8 + j];           // dst row chunk (f16)

        __half2 acc[4];
#pragma unroll
        for (int q = 0; q < 4; ++q) acc[q] = __float2half2_rn(0.f);

        // prologue: batch 0
        bool v[4]; uint4 raw[4];
#pragma unroll
        for (int u = 0; u < 4; ++u) {
            int ee = eStart + u;
            v[u] = ee < eEnd;
            int cc = col[v[u] ? ee : 0];
            raw[u] = XpV[(size_t)cc * 8 + j];
        }

        for (int e = eStart; e < eEnd; e += 4) {
            // issue batch i+1 loads first
            bool v2[4]; uint4 raw2[4];
#pragma unroll
            for (int u = 0; u < 4; ++u) {
                int ee = e + 4 + u;
                v2[u] = ee < eEnd;
                int cc = col[v2[u] ? ee : 0];
                raw2[u] = XpV[(size_t)cc * 8 + j];
            }
            // consume batch i
            float p[4];
#pragma unroll
            for (int u = 0; u < 4; ++u) p[u] = dot8_f16(xr, raw[u], 0.f);
#pragma unroll
            for (int off = 1; off < 8; off <<= 1)
#pragma unroll
                for (int u = 0; u < 4; ++u) p[u] += __shfl_xor(p[u], off, 64);
#pragma unroll
            for (int u = 0; u < 4; ++u) {
                __half2 sh = __float2half2_rn(v[u] ? p[u] : 0.f);
                const __half2* xh = (const __half2*)&raw[u];
#pragma unroll
                for (int q = 0; q < 4; ++q) acc[q] = __hfma2(sh, xh[q], acc[q]);
            }
#pragma unroll
            for (int u = 0; u < 4; ++u) { v[u] = v2[u]; raw[u] = raw2[u]; }
        }

        if (active) {
            float2 f0 = __half22float2(acc[0]);
            float2 f1 = __half22float2(acc[1]);
            float2 f2 = __half22float2(acc[2]);
            float2 f3 = __half22float2(acc[3]);
            float4* o = (float4*)(out + (size_t)node * D + 8 * j);
            o[0] = make_float4(attn * f0.x, attn * f0.y, attn * f1.x, attn * f1.y);
            o[1] = make_float4(attn * f2.x, attn * f2.y, attn * f3.x, attn * f3.y);
        }
    }
}

extern "C" void kernel_launch(void* const* d_in, const int* in_sizes, int n_in,
                              void* d_out, int out_size, void* d_ws, size_t ws_size,
                              hipStream_t stream) {
    const float* X    = (const float*)d_in[0];
    const float* W    = (const float*)d_in[1];
    const float* attn = (const float*)d_in[2];
    const int*   row  = (const int*)d_in[3];
    const int*   col  = (const int*)d_in[4];
    float* out = (float*)d_out;

    int nNodes = in_sizes[0] / D;
    int nEdges = in_sizes[3];

    // workspace layout: Xp_f16 [nNodes*D] | rowptr [nNodes+1] | workCtr [1]
    __half* Xp  = (__half*)d_ws;
    int* rowptr = (int*)((char*)d_ws + (size_t)nNodes * D * sizeof(__half));
    int* workCtr = rowptr + (nNodes + 1);

    int gemmBlocks = 1024;
    int rpBlocks   = (nEdges + 255) / 256;
    prep_kernel<<<gemmBlocks + rpBlocks, 256, 0, stream>>>(X, W, row, Xp, rowptr,
                                                           workCtr, nNodes, nEdges,
                                                           gemmBlocks);

    // persistent grid: 1024 blocks = 4 waves/SIMD; waves self-schedule octets
    fused_kernel<<<1024, 256, 0, stream>>>(Xp, rowptr, col, attn, workCtr, out, nNodes);
}

// Round 8
// 105.302 us; speedup vs baseline: 2.0125x; 2.0125x over previous
//
#include <hip/hip_runtime.h>
#include <hip/hip_fp16.h>

#define D 64

typedef _Float16 h16;
typedef h16 h16x2 __attribute__((ext_vector_type(2)));

__device__ __forceinline__ h16x2 u2h(unsigned int u) {
    union { unsigned int i; h16x2 h; } t; t.i = u; return t.h;
}

// dot of 8 f16 pairs (two uint4-packed rows), f32 accumulate
__device__ __forceinline__ float dot8_f16(uint4 a, uint4 b, float c) {
#if __has_builtin(__builtin_amdgcn_fdot2)
    c = __builtin_amdgcn_fdot2(u2h(a.x), u2h(b.x), c, false);
    c = __builtin_amdgcn_fdot2(u2h(a.y), u2h(b.y), c, false);
    c = __builtin_amdgcn_fdot2(u2h(a.z), u2h(b.z), c, false);
    c = __builtin_amdgcn_fdot2(u2h(a.w), u2h(b.w), c, false);
    return c;
#else
    float2 t, s;
    t = __half22float2(*(const __half2*)&a.x); s = __half22float2(*(const __half2*)&b.x);
    c = fmaf(t.x, s.x, c); c = fmaf(t.y, s.y, c);
    t = __half22float2(*(const __half2*)&a.y); s = __half22float2(*(const __half2*)&b.y);
    c = fmaf(t.x, s.x, c); c = fmaf(t.y, s.y, c);
    t = __half22float2(*(const __half2*)&a.z); s = __half22float2(*(const __half2*)&b.z);
    c = fmaf(t.x, s.x, c); c = fmaf(t.y, s.y, c);
    t = __half22float2(*(const __half2*)&a.w); s = __half22float2(*(const __half2*)&b.w);
    c = fmaf(t.x, s.x, c); c = fmaf(t.y, s.y, c);
    return c;
#endif
}

// ---------------------------------------------------------------------------
// Kernel 1 (merged): blocks [0, gemmBlocks) compute Xp = f16(X @ W);
// blocks [gemmBlocks, ...) build CSR rowptr from sorted `row`.
// ---------------------------------------------------------------------------
__global__ __launch_bounds__(256) void prep_kernel(const float* __restrict__ X,
                                                   const float* __restrict__ W,
                                                   const int* __restrict__ row,
                                                   __half* __restrict__ Xp,
                                                   int* __restrict__ rowptr,
                                                   int nNodes, int nEdges,
                                                   int gemmBlocks) {
    if ((int)blockIdx.x >= gemmBlocks) {
        int e = (blockIdx.x - gemmBlocks) * 256 + threadIdx.x;
        if (e >= nEdges) return;
        int r = row[e];
        int rprev = (e == 0) ? -1 : row[e - 1];
        for (int q = rprev + 1; q <= r; ++q) rowptr[q] = e;
        if (e == nEdges - 1) {
            for (int q = r + 1; q <= nNodes; ++q) rowptr[q] = nEdges;
        }
        return;
    }
    int lane = threadIdx.x & 63;
    int wave = (blockIdx.x * 256 + threadIdx.x) >> 6;
    int nWaves = gemmBlocks * 4;

    float w[D];
#pragma unroll
    for (int k = 0; k < D; ++k) w[k] = W[k * D + lane];

    for (int r = wave; r < nNodes; r += nWaves) {
        int rr = __builtin_amdgcn_readfirstlane(r);
        const float4* xr = (const float4*)(X + (size_t)rr * D);
        float acc = 0.f;
#pragma unroll
        for (int k4 = 0; k4 < D / 4; ++k4) {
            float4 xv = xr[k4];
            acc = fmaf(xv.x, w[4 * k4 + 0], acc);
            acc = fmaf(xv.y, w[4 * k4 + 1], acc);
            acc = fmaf(xv.z, w[4 * k4 + 2], acc);
            acc = fmaf(xv.w, w[4 * k4 + 3], acc);
        }
        Xp[(size_t)rr * D + lane] = __float2half(acc);
    }
}

// ---------------------------------------------------------------------------
// Kernel 2: fused SDDMM + SpMM. STATIC wave->octet map (no atomics — the
// round-7 work-stealing counter serialized across XCDs). One 8-lane group
// per node (8 nodes/wave); lane j holds dims 8j..8j+7 (uint4 of f16).
// Batches of 8 edges, double-buffered: batch i+1's col loads + gathers are
// issued before batch i is consumed (8+8 gathers in flight per lane).
// Dot = 4 x v_dot2_f32_f16; one 3-stage shfl reduce covers 8 edges; accum =
// 4 x v_pk_fma_f16. attn applied once in the f32 epilogue. Coalesced stores.
// ---------------------------------------------------------------------------
__global__ __launch_bounds__(256) void fused_kernel(const __half* __restrict__ Xp,
                                                    const int* __restrict__ rowptr,
                                                    const int* __restrict__ col,
                                                    const float* __restrict__ attn_w,
                                                    float* __restrict__ out,
                                                    int nNodes) {
    int lane = threadIdx.x & 63;
    int waveId = (blockIdx.x * 256 + threadIdx.x) >> 6;
    int g = lane >> 3;        // node slot within wave
    int j = lane & 7;         // dim chunk: dims 8j..8j+7

    int node = waveId * 8 + g;
    bool active = node < nNodes;
    int nd = active ? node : 0;

    int eStart = rowptr[nd];
    int eEnd   = active ? rowptr[nd + 1] : eStart;

    const uint4* XpV = (const uint4*)Xp;              // row stride = 8 uint4
    uint4 xr = XpV[(size_t)nd * 8 + j];               // dst row chunk (f16)

    __half2 acc[4];
#pragma unroll
    for (int q = 0; q < 4; ++q) acc[q] = __float2half2_rn(0.f);

    // prologue: batch 0 (safe index 0 for out-of-range slots)
    bool v[8]; uint4 raw[8];
#pragma unroll
    for (int u = 0; u < 8; ++u) {
        int ee = eStart + u;
        v[u] = ee < eEnd;
        int cc = col[v[u] ? ee : 0];
        raw[u] = XpV[(size_t)cc * 8 + j];
    }

    for (int e = eStart; e < eEnd; e += 8) {
        // ---- issue batch i+1 loads first (overlap with batch i consume) ----
        bool v2[8]; uint4 raw2[8];
#pragma unroll
        for (int u = 0; u < 8; ++u) {
            int ee = e + 8 + u;
            v2[u] = ee < eEnd;
            int cc = col[v2[u] ? ee : 0];
            raw2[u] = XpV[(size_t)cc * 8 + j];
        }
        // ---- consume batch i: 8 dots, one 3-stage reduce, 8 accumulates ----
        float p[8];
#pragma unroll
        for (int u = 0; u < 8; ++u) p[u] = dot8_f16(xr, raw[u], 0.f);
#pragma unroll
        for (int off = 1; off < 8; off <<= 1)
#pragma unroll
            for (int u = 0; u < 8; ++u) p[u] += __shfl_xor(p[u], off, 64);
#pragma unroll
        for (int u = 0; u < 8; ++u) {
            __half2 sh = __float2half2_rn(v[u] ? p[u] : 0.f);
            const __half2* xh = (const __half2*)&raw[u];
#pragma unroll
            for (int q = 0; q < 4; ++q) acc[q] = __hfma2(sh, xh[q], acc[q]);
        }
        // ---- rotate ----
#pragma unroll
        for (int u = 0; u < 8; ++u) { v[u] = v2[u]; raw[u] = raw2[u]; }
    }

    if (active) {
        float attn = attn_w[0];
        float2 f0 = __half22float2(acc[0]);
        float2 f1 = __half22float2(acc[1]);
        float2 f2 = __half22float2(acc[2]);
        float2 f3 = __half22float2(acc[3]);
        float4* o = (float4*)(out + (size_t)node * D + 8 * j);
        o[0] = make_float4(attn * f0.x, attn * f0.y, attn * f1.x, attn * f1.y);
        o[1] = make_float4(attn * f2.x, attn * f2.y, attn * f3.x, attn * f3.y);
    }
}

extern "C" void kernel_launch(void* const* d_in, const int* in_sizes, int n_in,
                              void* d_out, int out_size, void* d_ws, size_t ws_size,
                              hipStream_t stream) {
    const float* X    = (const float*)d_in[0];
    const float* W    = (const float*)d_in[1];
    const float* attn = (const float*)d_in[2];
    const int*   row  = (const int*)d_in[3];
    const int*   col  = (const int*)d_in[4];
    float* out = (float*)d_out;

    int nNodes = in_sizes[0] / D;
    int nEdges = in_sizes[3];

    // workspace layout: Xp_f16 [nNodes*D] | rowptr [nNodes+1]
    __half* Xp  = (__half*)d_ws;
    int* rowptr = (int*)((char*)d_ws + (size_t)nNodes * D * sizeof(__half));

    int gemmBlocks = 1024;
    int rpBlocks   = (nEdges + 255) / 256;
    prep_kernel<<<gemmBlocks + rpBlocks, 256, 0, stream>>>(X, W, row, Xp, rowptr,
                                                           nNodes, nEdges, gemmBlocks);

    int waves = (nNodes + 7) / 8;                        // 8 nodes per wave
    fused_kernel<<<(waves + 3) / 4, 256, 0, stream>>>(Xp, rowptr, col, attn, out, nNodes);
}